// Round 2
// baseline (98.588 us; speedup 1.0000x reference)
//
#include <hip/hip_runtime.h>

#define IH 128
#define IW 128
#define NCH (8*128)
#define V 8          // input rows per thread
#define CPT 4        // input cols per thread

// Bicubic a=-0.75 half-pixel 2x upsample taps.
// we = kern(-0.25) = [-0.10546875, 0.87890625, 0.26171875, -0.03515625]
// wo = reverse(we)
__global__ __launch_bounds__(256) void pyrup_bicubic_kernel(
        const float* __restrict__ in, float* __restrict__ out) {
    const int id = blockIdx.x * blockDim.x + threadIdx.x;
    const int cx = id & 31;          // col-group 0..31 (4 input cols each)
    const int ry = (id >> 5) & 15;   // row-strip 0..15 (8 input rows each)
    const int nc = id >> 9;          // 0..NCH-1

    const float* src = in + (size_t)nc * (IH * IW);
    float* dst = out + (size_t)nc * (size_t)(2 * IH) * (2 * IW);

    const int b = cx * CPT;          // base input col
    const int R = ry * V;            // base input row

    const float we0 = -0.10546875f, we1 = 0.87890625f,
                we2 =  0.26171875f, we3 = -0.03515625f;

    const bool interior = (cx >= 1) && (cx <= 30);

    // rolling window of horizontal-pass results: rows j-4..j after update
    float h0[5][CPT];   // even-output-col dot per input col
    float h1[5][CPT];   // odd-output-col dot per input col
#pragma unroll
    for (int w = 0; w < 5; ++w)
#pragma unroll
        for (int cp = 0; cp < CPT; ++cp) { h0[w][cp] = 0.f; h1[w][cp] = 0.f; }

#pragma unroll
    for (int jj = 0; jj < V + 4; ++jj) {
        int j = R - 2 + jj;
        j = min(max(j, 0), IH - 1);
        const float* row = src + j * IW;

        float c[8];   // input cols b-2 .. b+5
        if (interior) {
            float2 lo  = *reinterpret_cast<const float2*>(row + b - 2);
            float4 mid = *reinterpret_cast<const float4*>(row + b);
            float2 hi  = *reinterpret_cast<const float2*>(row + b + 4);
            c[0] = lo.x; c[1] = lo.y;
            c[2] = mid.x; c[3] = mid.y; c[4] = mid.z; c[5] = mid.w;
            c[6] = hi.x; c[7] = hi.y;
        } else {
#pragma unroll
            for (int k = 0; k < 8; ++k) {
                int cc = min(max(b - 2 + k, 0), IW - 1);
                c[k] = row[cc];
            }
        }

        // shift window (fully unrolled -> register renames, no moves)
#pragma unroll
        for (int w = 0; w < 4; ++w)
#pragma unroll
            for (int cp = 0; cp < CPT; ++cp) {
                h0[w][cp] = h0[w + 1][cp];
                h1[w][cp] = h1[w + 1][cp];
            }

        // horizontal pass for this row: input col p = b+cp
#pragma unroll
        for (int cp = 0; cp < CPT; ++cp) {
            // even out col (2p): taps over cols p-2..p+1 = c[cp..cp+3]
            h0[4][cp] = we3 * c[cp] + we2 * c[cp + 1] + we1 * c[cp + 2] + we0 * c[cp + 3];
            // odd out col (2p+1): taps over cols p-1..p+2 = c[cp+1..cp+4]
            h1[4][cp] = we0 * c[cp + 1] + we1 * c[cp + 2] + we2 * c[cp + 3] + we3 * c[cp + 4];
        }

        // once window holds rows i-2..i+2 (i = R+jj-4), emit output rows 2i, 2i+1
        if (jj >= 4) {
            const int i = R + jj - 4;
            float ev[2 * CPT], od[2 * CPT];
#pragma unroll
            for (int cp = 0; cp < CPT; ++cp) {
                // even out row (2i): rows i-2..i+1 -> window 0..3
                ev[2 * cp]     = we3 * h0[0][cp] + we2 * h0[1][cp] + we1 * h0[2][cp] + we0 * h0[3][cp];
                ev[2 * cp + 1] = we3 * h1[0][cp] + we2 * h1[1][cp] + we1 * h1[2][cp] + we0 * h1[3][cp];
                // odd out row (2i+1): rows i-1..i+2 -> window 1..4
                od[2 * cp]     = we0 * h0[1][cp] + we1 * h0[2][cp] + we2 * h0[3][cp] + we3 * h0[4][cp];
                od[2 * cp + 1] = we0 * h1[1][cp] + we1 * h1[2][cp] + we2 * h1[3][cp] + we3 * h1[4][cp];
            }
            size_t off = (size_t)(2 * i) * (2 * IW) + 2 * b;
            *reinterpret_cast<float4*>(dst + off)              = make_float4(ev[0], ev[1], ev[2], ev[3]);
            *reinterpret_cast<float4*>(dst + off + 4)          = make_float4(ev[4], ev[5], ev[6], ev[7]);
            *reinterpret_cast<float4*>(dst + off + 2 * IW)     = make_float4(od[0], od[1], od[2], od[3]);
            *reinterpret_cast<float4*>(dst + off + 2 * IW + 4) = make_float4(od[4], od[5], od[6], od[7]);
        }
    }
}

extern "C" void kernel_launch(void* const* d_in, const int* in_sizes, int n_in,
                              void* d_out, int out_size, void* d_ws, size_t ws_size,
                              hipStream_t stream) {
    const float* x = (const float*)d_in[0];
    float* out = (float*)d_out;
    // one thread per (4-col x 8-row) input patch
    const int total = NCH * (IH / V) * (IW / CPT);   // 1024 * 16 * 32 = 524288
    const int block = 256;
    const int grid = total / block;                   // 2048
    pyrup_bicubic_kernel<<<grid, block, 0, stream>>>(x, out);
}

// Round 3
// 79.901 us; speedup vs baseline: 1.2339x; 1.2339x over previous
//
#include <hip/hip_runtime.h>

#define IH 128
#define IW 128
#define NCH (8*128)
#define V 8          // input rows per thread

// Bicubic a=-0.75 half-pixel 2x upsample taps.
// we = kern(-0.25) = [-0.10546875, 0.87890625, 0.26171875, -0.03515625]
// wo = reverse(we)
__global__ __launch_bounds__(256) void pyrup_bicubic_kernel(
        const float* __restrict__ in, float* __restrict__ out) {
    const int id = blockIdx.x * blockDim.x + threadIdx.x;
    const int cx = id & 63;          // 64 col-groups of 2 input cols (wave = full row-strip)
    const int ry = (id >> 6) & 15;   // 16 row-strips of 8 input rows
    const int nc = id >> 10;         // 0..NCH-1

    const float* src = in + (size_t)nc * (IH * IW);
    float* dst = out + (size_t)nc * (size_t)(2 * IH) * (2 * IW);

    const int b = cx * 2;            // base input col
    const int R = ry * V;            // base input row

    const float we0 = -0.10546875f, we1 = 0.87890625f,
                we2 =  0.26171875f, we3 = -0.03515625f;

    // branch-free clamped load bases (all 8B-aligned)
    const bool at_lo = (cx == 0);
    const bool at_hi = (cx == 63);
    const int lo_off = at_lo ? 0 : (b - 2);
    const int hi_off = at_hi ? (IW - 2) : (b + 2);

    // rolling window of horizontal-pass results
    float h0[5][2], h1[5][2];
#pragma unroll
    for (int w = 0; w < 5; ++w) {
        h0[w][0] = h0[w][1] = 0.f;
        h1[w][0] = h1[w][1] = 0.f;
    }

#pragma unroll
    for (int jj = 0; jj < V + 4; ++jj) {
        int j = R - 2 + jj;
        j = min(max(j, 0), IH - 1);
        const float* row = src + j * IW;

        float2 v0 = *reinterpret_cast<const float2*>(row + lo_off);
        float2 v1 = *reinterpret_cast<const float2*>(row + b);
        float2 v2 = *reinterpret_cast<const float2*>(row + hi_off);

        // cols b-2 .. b+3 with edge clamping via selects (no divergence)
        float c0 = v0.x;
        float c1 = at_lo ? v0.x : v0.y;
        float c2 = v1.x;
        float c3 = v1.y;
        float c4 = at_hi ? v2.y : v2.x;
        float c5 = v2.y;

        // shift window (unrolled -> register renames)
#pragma unroll
        for (int w = 0; w < 4; ++w) {
            h0[w][0] = h0[w + 1][0]; h0[w][1] = h0[w + 1][1];
            h1[w][0] = h1[w + 1][0]; h1[w][1] = h1[w + 1][1];
        }

        // horizontal pass: input cols p = b, b+1
        h0[4][0] = we3 * c0 + we2 * c1 + we1 * c2 + we0 * c3;  // out col 2b
        h1[4][0] = we0 * c1 + we1 * c2 + we2 * c3 + we3 * c4;  // out col 2b+1
        h0[4][1] = we3 * c1 + we2 * c2 + we1 * c3 + we0 * c4;  // out col 2b+2
        h1[4][1] = we0 * c2 + we1 * c3 + we2 * c4 + we3 * c5;  // out col 2b+3

        // window holds rows i-2..i+2 (i = R+jj-4): emit output rows 2i, 2i+1
        if (jj >= 4) {
            const int i = R + jj - 4;
            float4 ev, od;
            // even out row (2i): rows i-2..i+1 -> window 0..3, wo taps
            ev.x = we3 * h0[0][0] + we2 * h0[1][0] + we1 * h0[2][0] + we0 * h0[3][0];
            ev.y = we3 * h1[0][0] + we2 * h1[1][0] + we1 * h1[2][0] + we0 * h1[3][0];
            ev.z = we3 * h0[0][1] + we2 * h0[1][1] + we1 * h0[2][1] + we0 * h0[3][1];
            ev.w = we3 * h1[0][1] + we2 * h1[1][1] + we1 * h1[2][1] + we0 * h1[3][1];
            // odd out row (2i+1): rows i-1..i+2 -> window 1..4, we taps
            od.x = we0 * h0[1][0] + we1 * h0[2][0] + we2 * h0[3][0] + we3 * h0[4][0];
            od.y = we0 * h1[1][0] + we1 * h1[2][0] + we2 * h1[3][0] + we3 * h1[4][0];
            od.z = we0 * h0[1][1] + we1 * h0[2][1] + we2 * h0[3][1] + we3 * h0[4][1];
            od.w = we0 * h1[1][1] + we1 * h1[2][1] + we2 * h1[3][1] + we3 * h1[4][1];

            size_t off = (size_t)(2 * i) * (2 * IW) + 4 * cx;
            *reinterpret_cast<float4*>(dst + off)            = ev;
            *reinterpret_cast<float4*>(dst + off + 2 * IW)   = od;
        }
    }
}

extern "C" void kernel_launch(void* const* d_in, const int* in_sizes, int n_in,
                              void* d_out, int out_size, void* d_ws, size_t ws_size,
                              hipStream_t stream) {
    const float* x = (const float*)d_in[0];
    float* out = (float*)d_out;
    // one thread per (2-col x 8-row) input patch
    const int total = NCH * (IH / V) * (IW / 2);   // 1024 * 16 * 64 = 1048576
    const int block = 256;
    const int grid = total / block;                 // 4096
    pyrup_bicubic_kernel<<<grid, block, 0, stream>>>(x, out);
}

// Round 4
// 67.906 us; speedup vs baseline: 1.4518x; 1.1766x over previous
//
#include <hip/hip_runtime.h>

#define IH 128
#define IW 128
#define NCH (8*128)
#define SR 16          // input rows per block strip
#define HR (SR + 4)    // h-plane rows incl. +/-2 halo = 20

// Bicubic a=-0.75 half-pixel 2x upsample taps (we; wo = reverse(we)).
__global__ __launch_bounds__(256) void pyrup_bicubic_kernel(
        const float* __restrict__ in, float* __restrict__ out) {
    __shared__ float h0s[HR][IW];   // even-output-col horizontal dots
    __shared__ float h1s[HR][IW];   // odd-output-col horizontal dots

    const int t = threadIdx.x;
    const int strip = blockIdx.x & 7;   // 8 strips of SR rows
    const int nc = blockIdx.x >> 3;
    const int R = strip * SR;

    const float* src = in + (size_t)nc * (IH * IW);
    float* dst = out + (size_t)nc * (size_t)(2 * IH) * (2 * IW);

    const float we0 = -0.10546875f, we1 = 0.87890625f,
                we2 =  0.26171875f, we3 = -0.03515625f;

    // ---- Phase 1: horizontal pass -> LDS (each input row handled once) ----
    const int g  = t & 31;    // col group: cols 4g..4g+3
    const int r0 = t >> 5;    // 0..7 row slot (wave = 2 rows x 32 col groups)
#pragma unroll
    for (int s = 0; s < 3; ++s) {
        const int l = r0 + 8 * s;          // local h-plane row 0..19
        if (l < HR) {                       // sweep 3: waves 2,3 skip whole-wave
            int j = min(max(R - 2 + l, 0), IH - 1);
            float4 v = *reinterpret_cast<const float4*>(src + j * IW + 4 * g);
            float c0 = v.x, c1 = v.y, c2 = v.z, c3 = v.w;
            // halo cols from neighbor lanes; edge lanes clamp (replicate pad)
            float lm2 = __shfl_up(c2, 1);
            float lm1 = __shfl_up(c3, 1);
            float rp4 = __shfl_down(c0, 1);
            float rp5 = __shfl_down(c1, 1);
            float a0 = (g == 0)  ? c0 : lm2;   // col 4g-2
            float a1 = (g == 0)  ? c0 : lm1;   // col 4g-1
            float a6 = (g == 31) ? c3 : rp4;   // col 4g+4
            float a7 = (g == 31) ? c3 : rp5;   // col 4g+5
            float4 H0, H1;
            // h0[p] (even out col 2p): taps p-2..p+1; h1[p] (odd): p-1..p+2
            H0.x = we3*a0 + we2*a1 + we1*c0 + we0*c1;
            H1.x = we0*a1 + we1*c0 + we2*c1 + we3*c2;
            H0.y = we3*a1 + we2*c0 + we1*c1 + we0*c2;
            H1.y = we0*c0 + we1*c1 + we2*c2 + we3*c3;
            H0.z = we3*c0 + we2*c1 + we1*c2 + we0*c3;
            H1.z = we0*c1 + we1*c2 + we2*c3 + we3*a6;
            H0.w = we3*c1 + we2*c2 + we1*c3 + we0*a6;
            H1.w = we0*c2 + we1*c3 + we2*a6 + we3*a7;
            *reinterpret_cast<float4*>(&h0s[l][4 * g]) = H0;
            *reinterpret_cast<float4*>(&h1s[l][4 * g]) = H1;
        }
    }
    __syncthreads();

    // ---- Phase 2: vertical pass + coalesced float4 stores ----
    const int q  = t & 63;          // col pair: input cols 2q,2q+1 -> out cols 4q..4q+3
    const int i0 = (t >> 6) * 4;    // 4 input rows per thread

    float2 w0[8], w1[8];
#pragma unroll
    for (int w = 0; w < 8; ++w) {   // h rows i0..i0+7 (window for rows i0..i0+3)
        w0[w] = *reinterpret_cast<const float2*>(&h0s[i0 + w][2 * q]);
        w1[w] = *reinterpret_cast<const float2*>(&h1s[i0 + w][2 * q]);
    }
#pragma unroll
    for (int w = 0; w < 4; ++w) {
        const int gi = R + i0 + w;   // global input row
        float4 ev, od;
        // even out row 2gi: h rows gi-2..gi+1 -> window w..w+3 (taps we3..we0)
        ev.x = we3*w0[w].x + we2*w0[w+1].x + we1*w0[w+2].x + we0*w0[w+3].x;
        ev.y = we3*w1[w].x + we2*w1[w+1].x + we1*w1[w+2].x + we0*w1[w+3].x;
        ev.z = we3*w0[w].y + we2*w0[w+1].y + we1*w0[w+2].y + we0*w0[w+3].y;
        ev.w = we3*w1[w].y + we2*w1[w+1].y + we1*w1[w+2].y + we0*w1[w+3].y;
        // odd out row 2gi+1: h rows gi-1..gi+2 -> window w+1..w+4 (taps we0..we3)
        od.x = we0*w0[w+1].x + we1*w0[w+2].x + we2*w0[w+3].x + we3*w0[w+4].x;
        od.y = we0*w1[w+1].x + we1*w1[w+2].x + we2*w1[w+3].x + we3*w1[w+4].x;
        od.z = we0*w0[w+1].y + we1*w0[w+2].y + we2*w0[w+3].y + we3*w0[w+4].y;
        od.w = we0*w1[w+1].y + we1*w1[w+2].y + we2*w1[w+3].y + we3*w1[w+4].y;
        size_t off = (size_t)(2 * gi) * (2 * IW) + 4 * q;
        *reinterpret_cast<float4*>(dst + off)            = ev;
        *reinterpret_cast<float4*>(dst + off + 2 * IW)   = od;
    }
}

extern "C" void kernel_launch(void* const* d_in, const int* in_sizes, int n_in,
                              void* d_out, int out_size, void* d_ws, size_t ws_size,
                              hipStream_t stream) {
    const float* x = (const float*)d_in[0];
    float* out = (float*)d_out;
    const int grid = NCH * (IH / SR);   // 1024 * 8 = 8192 blocks
    pyrup_bicubic_kernel<<<grid, 256, 0, stream>>>(x, out);
}

// Round 6
// 57.084 us; speedup vs baseline: 1.7271x; 1.1896x over previous
//
#include <hip/hip_runtime.h>

#define IH 128
#define IW 128
#define NCH (8*128)
#define SR 16          // input rows per block strip
#define HR (SR + 4)    // h-plane rows incl. +/-2 halo = 20

typedef float f32x4 __attribute__((ext_vector_type(4)));

// Bicubic a=-0.75 half-pixel 2x upsample taps (we; wo = reverse(we)).
__global__ __launch_bounds__(256) void pyrup_bicubic_kernel(
        const float* __restrict__ in, float* __restrict__ out) {
    __shared__ float h0s[HR][IW];   // even-output-col horizontal dots
    __shared__ float h1s[HR][IW];   // odd-output-col horizontal dots

    const int t = threadIdx.x;
    const int strip = blockIdx.x & 7;   // 8 strips of SR rows
    const int nc = blockIdx.x >> 3;
    const int R = strip * SR;

    const float* src = in + (size_t)nc * (IH * IW);
    float* dst = out + (size_t)nc * (size_t)(2 * IH) * (2 * IW);

    const float we0 = -0.10546875f, we1 = 0.87890625f,
                we2 =  0.26171875f, we3 = -0.03515625f;

    // ---- Phase 1: horizontal pass -> LDS (each input row handled once) ----
    const int g  = t & 31;    // col group: cols 4g..4g+3
    const int r0 = t >> 5;    // 0..7 row slot (wave = 2 rows x 32 col groups)
#pragma unroll
    for (int s = 0; s < 3; ++s) {
        const int l = r0 + 8 * s;          // local h-plane row 0..19
        if (l < HR) {                       // sweep 3: waves 2,3 skip whole-wave
            int j = min(max(R - 2 + l, 0), IH - 1);
            float4 v = *reinterpret_cast<const float4*>(src + j * IW + 4 * g);
            float c0 = v.x, c1 = v.y, c2 = v.z, c3 = v.w;
            // halo cols from neighbor lanes; edge lanes clamp (replicate pad)
            float lm2 = __shfl_up(c2, 1);
            float lm1 = __shfl_up(c3, 1);
            float rp4 = __shfl_down(c0, 1);
            float rp5 = __shfl_down(c1, 1);
            float a0 = (g == 0)  ? c0 : lm2;   // col 4g-2
            float a1 = (g == 0)  ? c0 : lm1;   // col 4g-1
            float a6 = (g == 31) ? c3 : rp4;   // col 4g+4
            float a7 = (g == 31) ? c3 : rp5;   // col 4g+5
            float4 H0, H1;
            // h0[p] (even out col 2p): taps p-2..p+1; h1[p] (odd): p-1..p+2
            H0.x = we3*a0 + we2*a1 + we1*c0 + we0*c1;
            H1.x = we0*a1 + we1*c0 + we2*c1 + we3*c2;
            H0.y = we3*a1 + we2*c0 + we1*c1 + we0*c2;
            H1.y = we0*c0 + we1*c1 + we2*c2 + we3*c3;
            H0.z = we3*c0 + we2*c1 + we1*c2 + we0*c3;
            H1.z = we0*c1 + we1*c2 + we2*c3 + we3*a6;
            H0.w = we3*c1 + we2*c2 + we1*c3 + we0*a6;
            H1.w = we0*c2 + we1*c3 + we2*a6 + we3*a7;
            *reinterpret_cast<float4*>(&h0s[l][4 * g]) = H0;
            *reinterpret_cast<float4*>(&h1s[l][4 * g]) = H1;
        }
    }
    __syncthreads();

    // ---- Phase 2: vertical pass + coalesced non-temporal float4 stores ----
    const int q  = t & 63;          // col pair: input cols 2q,2q+1 -> out cols 4q..4q+3
    const int i0 = (t >> 6) * 4;    // 4 input rows per thread

    float2 w0[8], w1[8];
#pragma unroll
    for (int w = 0; w < 8; ++w) {   // h rows i0..i0+7 (window for rows i0..i0+3)
        w0[w] = *reinterpret_cast<const float2*>(&h0s[i0 + w][2 * q]);
        w1[w] = *reinterpret_cast<const float2*>(&h1s[i0 + w][2 * q]);
    }
#pragma unroll
    for (int w = 0; w < 4; ++w) {
        const int gi = R + i0 + w;   // global input row
        f32x4 ev, od;
        // even out row 2gi: h rows gi-2..gi+1 -> window w..w+3 (taps we3..we0)
        ev.x = we3*w0[w].x + we2*w0[w+1].x + we1*w0[w+2].x + we0*w0[w+3].x;
        ev.y = we3*w1[w].x + we2*w1[w+1].x + we1*w1[w+2].x + we0*w1[w+3].x;
        ev.z = we3*w0[w].y + we2*w0[w+1].y + we1*w0[w+2].y + we0*w0[w+3].y;
        ev.w = we3*w1[w].y + we2*w1[w+1].y + we1*w1[w+2].y + we0*w1[w+3].y;
        // odd out row 2gi+1: h rows gi-1..gi+2 -> window w+1..w+4 (taps we0..we3)
        od.x = we0*w0[w+1].x + we1*w0[w+2].x + we2*w0[w+3].x + we3*w0[w+4].x;
        od.y = we0*w1[w+1].x + we1*w1[w+2].x + we2*w1[w+3].x + we3*w1[w+4].x;
        od.z = we0*w0[w+1].y + we1*w0[w+2].y + we2*w0[w+3].y + we3*w0[w+4].y;
        od.w = we0*w1[w+1].y + we1*w1[w+2].y + we2*w1[w+3].y + we3*w1[w+4].y;
        size_t off = (size_t)(2 * gi) * (2 * IW) + 4 * q;
        __builtin_nontemporal_store(ev, reinterpret_cast<f32x4*>(dst + off));
        __builtin_nontemporal_store(od, reinterpret_cast<f32x4*>(dst + off + 2 * IW));
    }
}

extern "C" void kernel_launch(void* const* d_in, const int* in_sizes, int n_in,
                              void* d_out, int out_size, void* d_ws, size_t ws_size,
                              hipStream_t stream) {
    const float* x = (const float*)d_in[0];
    float* out = (float*)d_out;
    const int grid = NCH * (IH / SR);   // 1024 * 8 = 8192 blocks
    pyrup_bicubic_kernel<<<grid, 256, 0, stream>>>(x, out);
}

// Round 7
// 53.149 us; speedup vs baseline: 1.8549x; 1.0740x over previous
//
#include <hip/hip_runtime.h>

#define IH 128
#define IW 128
#define NCH (8*128)
#define SR 16          // input rows per block strip
#define HR (SR + 4)    // h-plane rows incl. +/-2 halo = 20

typedef float f32x4 __attribute__((ext_vector_type(4)));

// Bicubic a=-0.75 half-pixel 2x upsample taps (we; wo = reverse(we)).
__global__ __launch_bounds__(256) void pyrup_bicubic_kernel(
        const float* __restrict__ in, float* __restrict__ out) {
    // interleaved h-plane: hs[l][p] = (h0[2p], h1[2p], h0[2p+1], h1[2p+1])
    __shared__ f32x4 hs[HR][64];    // 20 KiB

    const int t = threadIdx.x;
    // XCD-chunked swizzle (bijective, 8192 blocks): all 8 strips of a
    // channel land on the same XCD -> halo rows + channel reuse hit L2.
    const int bid = blockIdx.x;
    const int wgid = (bid & 7) * 1024 + (bid >> 3);
    const int strip = wgid & 7;     // 8 strips of SR rows
    const int nc = wgid >> 3;       // channel 0..NCH-1
    const int R = strip * SR;

    const float* src = in + (size_t)nc * (IH * IW);
    float* dst = out + (size_t)nc * (size_t)(2 * IH) * (2 * IW);

    const float we0 = -0.10546875f, we1 = 0.87890625f,
                we2 =  0.26171875f, we3 = -0.03515625f;

    // ---- Phase 1: horizontal pass -> LDS (each input row handled once) ----
    const int g  = t & 31;    // col group: cols 4g..4g+3
    const int r0 = t >> 5;    // 0..7 row slot
#pragma unroll
    for (int s = 0; s < 3; ++s) {
        const int l = r0 + 8 * s;          // local h-plane row 0..19
        if (l < HR) {
            int j = min(max(R - 2 + l, 0), IH - 1);
            float4 v = *reinterpret_cast<const float4*>(src + j * IW + 4 * g);
            float c0 = v.x, c1 = v.y, c2 = v.z, c3 = v.w;
            // halo cols from neighbor lanes; edge lanes clamp (replicate pad)
            float lm2 = __shfl_up(c2, 1);
            float lm1 = __shfl_up(c3, 1);
            float rp4 = __shfl_down(c0, 1);
            float rp5 = __shfl_down(c1, 1);
            float a0 = (g == 0)  ? c0 : lm2;   // col 4g-2
            float a1 = (g == 0)  ? c0 : lm1;   // col 4g-1
            float a6 = (g == 31) ? c3 : rp4;   // col 4g+4
            float a7 = (g == 31) ? c3 : rp5;   // col 4g+5
            // h0[p] (even out col 2p): taps p-2..p+1; h1[p] (odd): p-1..p+2
            float h0x = we3*a0 + we2*a1 + we1*c0 + we0*c1;
            float h1x = we0*a1 + we1*c0 + we2*c1 + we3*c2;
            float h0y = we3*a1 + we2*c0 + we1*c1 + we0*c2;
            float h1y = we0*c0 + we1*c1 + we2*c2 + we3*c3;
            float h0z = we3*c0 + we2*c1 + we1*c2 + we0*c3;
            float h1z = we0*c1 + we1*c2 + we2*c3 + we3*a6;
            float h0w = we3*c1 + we2*c2 + we1*c3 + we0*a6;
            float h1w = we0*c2 + we1*c3 + we2*a6 + we3*a7;
            hs[l][2 * g]     = (f32x4){h0x, h1x, h0y, h1y};
            hs[l][2 * g + 1] = (f32x4){h0z, h1z, h0w, h1w};
        }
    }
    __syncthreads();

    // ---- Phase 2: vertical pass (vector FMA) + non-temporal stores ----
    const int q  = t & 63;          // col pair -> out cols 4q..4q+3
    const int i0 = (t >> 6) * 4;    // 4 input rows per thread

    f32x4 W[8];
#pragma unroll
    for (int w = 0; w < 8; ++w)     // 8 x ds_read_b128, lane-contiguous
        W[w] = hs[i0 + w][q];

#pragma unroll
    for (int w = 0; w < 4; ++w) {
        const int gi = R + i0 + w;  // global input row
        // even out row 2gi: taps we3..we0 over W[w..w+3]
        f32x4 ev = we3 * W[w] + we2 * W[w + 1] + we1 * W[w + 2] + we0 * W[w + 3];
        // odd out row 2gi+1: taps we0..we3 over W[w+1..w+4]
        f32x4 od = we0 * W[w + 1] + we1 * W[w + 2] + we2 * W[w + 3] + we3 * W[w + 4];
        size_t off = (size_t)(2 * gi) * (2 * IW) + 4 * q;
        __builtin_nontemporal_store(ev, reinterpret_cast<f32x4*>(dst + off));
        __builtin_nontemporal_store(od, reinterpret_cast<f32x4*>(dst + off + 2 * IW));
    }
}

extern "C" void kernel_launch(void* const* d_in, const int* in_sizes, int n_in,
                              void* d_out, int out_size, void* d_ws, size_t ws_size,
                              hipStream_t stream) {
    const float* x = (const float*)d_in[0];
    float* out = (float*)d_out;
    const int grid = NCH * (IH / SR);   // 1024 * 8 = 8192 blocks
    pyrup_bicubic_kernel<<<grid, 256, 0, stream>>>(x, out);
}